// Round 8
// baseline (407.726 us; speedup 1.0000x reference)
//
#include <hip/hip_runtime.h>
#include <hip/hip_bf16.h>
#include <math.h>

typedef unsigned short u16;
typedef __attribute__((ext_vector_type(8))) short short8;
typedef __attribute__((ext_vector_type(4))) float float4v;

#define MFMA_BF16(a, b, c) __builtin_amdgcn_mfma_f32_16x16x32_bf16((a), (b), (c), 0, 0, 0)

typedef const __attribute__((address_space(1))) void* gas_ptr;
typedef __attribute__((address_space(3))) void* las_ptr;

__device__ __forceinline__ u16 f2bf(float f) {
  __hip_bfloat16 h = __float2bfloat16(f);
  return __builtin_bit_cast(u16, h);
}

__device__ __forceinline__ float bf2f(u16 v) {
  return __builtin_bit_cast(float, (unsigned)v << 16);
}

__device__ __forceinline__ void load_lds16(const u16* g, u16* l) {
  __builtin_amdgcn_global_load_lds((gas_ptr)g, (las_ptr)l, 16, 0, 0);
}

// ---------------------------------------------------------------------------
// m97-style gemm_bt mainloop with general strides and K-window:
//   C[128x128] += A[m0.., kb..kend) * Bt[n0.., kb..kend)^T
// ---------------------------------------------------------------------------
__device__ __forceinline__ void gemm_mainloop(
    const u16* __restrict__ A, const u16* __restrict__ Bt,
    int kb, int kend, int lda, int ldb,
    int m0, int n0, u16* As, u16* Bs, float4v acc[4][4])
{
  const int tid = threadIdx.x;
  const int w = tid >> 6, lane = tid & 63;
  const int wr = w >> 1, wc = w & 1;
  const int lr = lane & 15, lk = (lane >> 4) * 8;
  for (int k0 = kb; k0 < kend; k0 += 32) {
#pragma unroll
    for (int c = 0; c < 2; ++c) {
      int idx = c * 256 + w * 64 + lane;
      int r = idx >> 2, c8 = idx & 3;
      load_lds16(A + (size_t)(m0 + r) * lda + k0 + c8 * 8, As + (size_t)(c * 256 + w * 64) * 8);
      load_lds16(Bt + (size_t)(n0 + r) * ldb + k0 + c8 * 8, Bs + (size_t)(c * 256 + w * 64) * 8);
    }
    __syncthreads();
    short8 af[4], bf[4];
#pragma unroll
    for (int mt = 0; mt < 4; ++mt)
      af[mt] = *(const short8*)&As[(wr * 64 + mt * 16 + lr) * 32 + lk];
#pragma unroll
    for (int nt = 0; nt < 4; ++nt)
      bf[nt] = *(const short8*)&Bs[(wc * 64 + nt * 16 + lr) * 32 + lk];
#pragma unroll
    for (int mt = 0; mt < 4; ++mt)
#pragma unroll
      for (int nt = 0; nt < 4; ++nt)
        acc[mt][nt] = MFMA_BF16(af[mt], bf[nt], acc[mt][nt]);
    __syncthreads();
  }
}

// ---------------------------------------------------------------------------
// GEMM 1: QKV projection
// ---------------------------------------------------------------------------
__global__ __launch_bounds__(256) void gemm_qkv(
    const u16* __restrict__ A, const u16* __restrict__ Bt,
    const float* __restrict__ bq, const float* __restrict__ bk, const float* __restrict__ bv,
    u16* __restrict__ qo, u16* __restrict__ ko, u16* __restrict__ vto)
{
  __shared__ u16 As[128 * 32], Bs[128 * 32];
  float4v acc[4][4];
#pragma unroll
  for (int mt = 0; mt < 4; ++mt)
#pragma unroll
    for (int nt = 0; nt < 4; ++nt) acc[mt][nt] = (float4v){0.f, 0.f, 0.f, 0.f};
  const int m0 = blockIdx.y * 128, n0 = blockIdx.x * 128;
  gemm_mainloop(A, Bt, 0, 512, 512, 512, m0, n0, As, Bs, acc);
  const int tid = threadIdx.x, w = tid >> 6, lane = tid & 63;
  const int wr = w >> 1, wc = w & 1, lr = lane & 15, lg = lane >> 4;
#pragma unroll
  for (int mt = 0; mt < 4; ++mt) {
#pragma unroll
    for (int nt = 0; nt < 4; ++nt) {
      int n = n0 + wc * 64 + nt * 16 + lr;
#pragma unroll
      for (int r = 0; r < 4; ++r) {
        int i = m0 + wr * 64 + mt * 16 + lg * 4 + r;
        float v = acc[mt][nt][r];
        if (n < 512) {
          qo[(size_t)i * 512 + n] = f2bf(v + bq[n]);
        } else if (n < 1024) {
          ko[(size_t)i * 512 + (n - 512)] = f2bf(v + bk[n - 512]);
        } else {
          int bb = i >> 12, t = i & 4095;
          vto[((size_t)(bb * 512 + (n - 1024))) * 4096 + t] = f2bf(v + bv[n - 1024]);
        }
      }
    }
  }
}

// ---------------------------------------------------------------------------
// Attention pass 1: P = exp(QK^T/sqrt(d) - ds*dist), causal, bf16 out.
// One batch per launch. Triangular tile grid (528 blocks). Row sums -> l
// via float atomics (l zeroed before).
// ---------------------------------------------------------------------------
__global__ __launch_bounds__(256) void gemm_qk_p(
    const u16* __restrict__ q, const u16* __restrict__ k,
    const float* __restrict__ dsp,
    u16* __restrict__ P, float* __restrict__ l)
{
  __shared__ u16 As[128 * 32], Bs[128 * 32];
  float4v acc[4][4];
#pragma unroll
  for (int mt = 0; mt < 4; ++mt)
#pragma unroll
    for (int nt = 0; nt < 4; ++nt) acc[mt][nt] = (float4v){0.f, 0.f, 0.f, 0.f};
  int idx = blockIdx.x;
  int tm = (int)((sqrtf(8.0f * (float)idx + 1.0f) - 1.0f) * 0.5f);
  while ((tm + 1) * (tm + 2) / 2 <= idx) ++tm;
  while (tm * (tm + 1) / 2 > idx) --tm;
  int tn = idx - tm * (tm + 1) / 2;
  const int m0 = tm * 128, n0 = tn * 128;
  gemm_mainloop(q, k, 0, 512, 512, 512, m0, n0, As, Bs, acc);
  const int tid = threadIdx.x, w = tid >> 6, lane = tid & 63;
  const int wr = w >> 1, wc = w & 1, lr = lane & 15, lg = lane >> 4;
  const float invs = 0.04419417382415922f;   // 1/sqrt(512)
  const float dsi = dsp[0] * invs;
  const float L2E = 1.4426950408889634f;
  float rs[4][4];
#pragma unroll
  for (int mt = 0; mt < 4; ++mt)
#pragma unroll
    for (int r = 0; r < 4; ++r) rs[mt][r] = 0.f;
#pragma unroll
  for (int mt = 0; mt < 4; ++mt) {
#pragma unroll
    for (int nt = 0; nt < 4; ++nt) {
      int j = n0 + wc * 64 + nt * 16 + lr;
#pragma unroll
      for (int r = 0; r < 4; ++r) {
        int i = m0 + wr * 64 + mt * 16 + lg * 4 + r;
        float x = acc[mt][nt][r] * invs - dsi * fabsf((float)(i - j));
        float p = (j > i) ? 0.f : exp2f(x * L2E);
        P[(size_t)i * 4096 + j] = f2bf(p);
        rs[mt][r] += p;
      }
    }
  }
#pragma unroll
  for (int mt = 0; mt < 4; ++mt) {
#pragma unroll
    for (int r = 0; r < 4; ++r) {
      float v = rs[mt][r];
#pragma unroll
      for (int off = 1; off < 16; off <<= 1) v += __shfl_xor(v, off, 64);
      if (lr == 0)
        atomicAdd(&l[m0 + wr * 64 + mt * 16 + lg * 4 + r], v);
    }
  }
}

// ---------------------------------------------------------------------------
// Attention pass 2: of += P @ V, equal-work K-chunks (<=512 k-elems = 16 iters).
// blockIdx.y encodes (tm, chunk): chunks per tm = (tm>>2)+1, total 144.
// Output accumulated via fp32 atomicAdd (of zeroed before launch).
// ---------------------------------------------------------------------------
__global__ __launch_bounds__(256) void gemm_pv(
    const u16* __restrict__ P, const u16* __restrict__ vt,
    float* __restrict__ of)
{
  __shared__ u16 As[128 * 32], Bs[128 * 32];
  float4v acc[4][4];
#pragma unroll
  for (int mt = 0; mt < 4; ++mt)
#pragma unroll
    for (int nt = 0; nt < 4; ++nt) acc[mt][nt] = (float4v){0.f, 0.f, 0.f, 0.f};
  // decode (tm, chunk) from blockIdx.y
  int rem = blockIdx.y;
  int tm = 0, cpt = 1;
  while (rem >= cpt) { rem -= cpt; ++tm; cpt = (tm >> 2) + 1; }
  const int m0 = tm * 128, n0 = blockIdx.x * 128;
  const int kb = rem * 512;
  const int kfull = (tm + 1) * 128;
  const int kend = (kb + 512 < kfull) ? (kb + 512) : kfull;
  gemm_mainloop(P, vt, kb, kend, 4096, 4096, m0, n0, As, Bs, acc);
  const int tid = threadIdx.x, w = tid >> 6, lane = tid & 63;
  const int wr = w >> 1, wc = w & 1, lr = lane & 15, lg = lane >> 4;
#pragma unroll
  for (int mt = 0; mt < 4; ++mt) {
#pragma unroll
    for (int nt = 0; nt < 4; ++nt) {
      int n = n0 + wc * 64 + nt * 16 + lr;
#pragma unroll
      for (int r = 0; r < 4; ++r) {
        int i = m0 + wr * 64 + mt * 16 + lg * 4 + r;
        atomicAdd(&of[(size_t)i * 512 + n], acc[mt][nt][r]);
      }
    }
  }
}

// ---------------------------------------------------------------------------
// GEMM: FFN1 (relu epilogue)
// ---------------------------------------------------------------------------
__global__ __launch_bounds__(256) void gemm_ffn1(
    const u16* __restrict__ A, const u16* __restrict__ Bt,
    const float* __restrict__ b1, u16* __restrict__ h)
{
  __shared__ u16 As[128 * 32], Bs[128 * 32];
  float4v acc[4][4];
#pragma unroll
  for (int mt = 0; mt < 4; ++mt)
#pragma unroll
    for (int nt = 0; nt < 4; ++nt) acc[mt][nt] = (float4v){0.f, 0.f, 0.f, 0.f};
  const int m0 = blockIdx.y * 128, n0 = blockIdx.x * 128;
  gemm_mainloop(A, Bt, 0, 512, 512, 512, m0, n0, As, Bs, acc);
  const int tid = threadIdx.x, w = tid >> 6, lane = tid & 63;
  const int wr = w >> 1, wc = w & 1, lr = lane & 15, lg = lane >> 4;
#pragma unroll
  for (int mt = 0; mt < 4; ++mt) {
#pragma unroll
    for (int nt = 0; nt < 4; ++nt) {
      int n = n0 + wc * 64 + nt * 16 + lr;
#pragma unroll
      for (int r = 0; r < 4; ++r) {
        int i = m0 + wr * 64 + mt * 16 + lg * 4 + r;
        h[(size_t)i * 2048 + n] = f2bf(fmaxf(acc[mt][nt][r] + b1[n], 0.f));
      }
    }
  }
}

// ---------------------------------------------------------------------------
// GEMM: FFN2, K=2048 split x4 (16 iters/block), atomicAdd into zeroed y.
// Bias b2 is applied in LN2.
// ---------------------------------------------------------------------------
__global__ __launch_bounds__(256) void gemm_ffn2(
    const u16* __restrict__ A, const u16* __restrict__ Bt,
    float* __restrict__ y)
{
  __shared__ u16 As[128 * 32], Bs[128 * 32];
  float4v acc[4][4];
#pragma unroll
  for (int mt = 0; mt < 4; ++mt)
#pragma unroll
    for (int nt = 0; nt < 4; ++nt) acc[mt][nt] = (float4v){0.f, 0.f, 0.f, 0.f};
  const int m0 = blockIdx.y * 128, n0 = blockIdx.x * 128;
  const int kb = blockIdx.z * 512;
  gemm_mainloop(A, Bt, kb, kb + 512, 2048, 2048, m0, n0, As, Bs, acc);
  const int tid = threadIdx.x, w = tid >> 6, lane = tid & 63;
  const int wr = w >> 1, wc = w & 1, lr = lane & 15, lg = lane >> 4;
#pragma unroll
  for (int mt = 0; mt < 4; ++mt) {
#pragma unroll
    for (int nt = 0; nt < 4; ++nt) {
      int n = n0 + wc * 64 + nt * 16 + lr;
#pragma unroll
      for (int r = 0; r < 4; ++r) {
        int i = m0 + wr * 64 + mt * 16 + lg * 4 + r;
        atomicAdd(&y[(size_t)i * 512 + n], acc[mt][nt][r]);
      }
    }
  }
}

// ---------------------------------------------------------------------------
// LN1: x = LN(attn/l + tokens); writes fp32 + bf16
// ---------------------------------------------------------------------------
__global__ __launch_bounds__(256) void ln1_kernel(
    const float* __restrict__ a, const float* __restrict__ lsum,
    const float* __restrict__ tok,
    const float* __restrict__ g, const float* __restrict__ be,
    float* __restrict__ of, u16* __restrict__ ob)
{
  const int row = blockIdx.x * 4 + (threadIdx.x >> 6);
  const int lane = threadIdx.x & 63;
  const size_t base = (size_t)row * 512 + lane * 8;
  const float linv = 1.0f / lsum[row];
  float v[8];
#pragma unroll
  for (int t = 0; t < 8; ++t)
    v[t] = a[base + t] * linv + tok[base + t];
  float s = 0.f;
#pragma unroll
  for (int t = 0; t < 8; ++t) s += v[t];
#pragma unroll
  for (int off = 1; off < 64; off <<= 1) s += __shfl_xor(s, off, 64);
  const float mu = s * (1.0f / 512.0f);
  float qv = 0.f;
#pragma unroll
  for (int t = 0; t < 8; ++t) { float d = v[t] - mu; qv += d * d; }
#pragma unroll
  for (int off = 1; off < 64; off <<= 1) qv += __shfl_xor(qv, off, 64);
  const float rs = rsqrtf(qv * (1.0f / 512.0f) + 1e-5f);
  const int cb = lane * 8;
#pragma unroll
  for (int t = 0; t < 8; ++t) {
    float xv = (v[t] - mu) * rs * g[cb + t] + be[cb + t];
    of[base + t] = xv;
    ob[base + t] = f2bf(xv);
  }
}

// ---------------------------------------------------------------------------
// LN2: out = LN(y + b2 + x)
// ---------------------------------------------------------------------------
__global__ __launch_bounds__(256) void ln2_kernel(
    const float* __restrict__ a, const float* __restrict__ b2,
    const float* __restrict__ bsrc,
    const float* __restrict__ g, const float* __restrict__ be,
    float* __restrict__ of)
{
  const int row = blockIdx.x * 4 + (threadIdx.x >> 6);
  const int lane = threadIdx.x & 63;
  const size_t base = (size_t)row * 512 + lane * 8;
  const int cb = lane * 8;
  float v[8];
#pragma unroll
  for (int t = 0; t < 8; ++t) v[t] = a[base + t] + b2[cb + t] + bsrc[base + t];
  float s = 0.f;
#pragma unroll
  for (int t = 0; t < 8; ++t) s += v[t];
#pragma unroll
  for (int off = 1; off < 64; off <<= 1) s += __shfl_xor(s, off, 64);
  const float mu = s * (1.0f / 512.0f);
  float qv = 0.f;
#pragma unroll
  for (int t = 0; t < 8; ++t) { float d = v[t] - mu; qv += d * d; }
#pragma unroll
  for (int off = 1; off < 64; off <<= 1) qv += __shfl_xor(qv, off, 64);
  const float rs = rsqrtf(qv * (1.0f / 512.0f) + 1e-5f);
#pragma unroll
  for (int t = 0; t < 8; ++t) {
    float xv = (v[t] - mu) * rs * g[cb + t] + be[cb + t];
    of[base + t] = xv;
  }
}

// ---------------------------------------------------------------------------
// prep kernels
// ---------------------------------------------------------------------------
__global__ __launch_bounds__(256) void cast_bf_kernel(
    const float* __restrict__ in, u16* __restrict__ out)
{
  const size_t i = ((size_t)blockIdx.x * 256 + threadIdx.x) * 8;
#pragma unroll
  for (int t = 0; t < 8; ++t) out[i + t] = f2bf(in[i + t]);
}

// Tiled transpose for the three 512x512 QKV weights in one launch (z = which).
__global__ __launch_bounds__(256) void transpose_qkv_kernel(
    const float* __restrict__ Wq, const float* __restrict__ Wk,
    const float* __restrict__ Wv, u16* __restrict__ dst)
{
  __shared__ u16 tile[32][33];
  const float* src = (blockIdx.z == 0) ? Wq : (blockIdx.z == 1) ? Wk : Wv;
  u16* d = dst + (size_t)blockIdx.z * 512 * 512;
  const int tx = threadIdx.x & 31, ty = threadIdx.x >> 5;
  const int n0 = blockIdx.x * 32, k0 = blockIdx.y * 32;
#pragma unroll
  for (int i = 0; i < 32; i += 8)
    tile[ty + i][tx] = f2bf(src[(size_t)(k0 + ty + i) * 512 + n0 + tx]);
  __syncthreads();
#pragma unroll
  for (int i = 0; i < 32; i += 8)
    d[(size_t)(n0 + ty + i) * 512 + k0 + tx] = tile[tx][ty + i];
}

__global__ __launch_bounds__(256) void transpose_bf_kernel(
    const float* __restrict__ src, u16* __restrict__ dst, int K, int N)
{
  __shared__ u16 tile[32][33];
  const int tx = threadIdx.x & 31, ty = threadIdx.x >> 5;
  const int n0 = blockIdx.x * 32, k0 = blockIdx.y * 32;
#pragma unroll
  for (int i = 0; i < 32; i += 8)
    tile[ty + i][tx] = f2bf(src[(size_t)(k0 + ty + i) * N + n0 + tx]);
  __syncthreads();
#pragma unroll
  for (int i = 0; i < 32; i += 8)
    dst[(size_t)(n0 + ty + i) * K + k0 + tx] = tile[tx][ty + i];
}

// ---------------------------------------------------------------------------
// launch
// ---------------------------------------------------------------------------
extern "C" void kernel_launch(void* const* d_in, const int* in_sizes, int n_in,
                              void* d_out, int out_size, void* d_ws, size_t ws_size,
                              hipStream_t stream) {
  const float* tokens = (const float*)d_in[0];
  const float* Wq = (const float*)d_in[1];
  const float* bq = (const float*)d_in[2];
  const float* Wk = (const float*)d_in[3];
  const float* bk = (const float*)d_in[4];
  const float* Wv = (const float*)d_in[5];
  const float* bv = (const float*)d_in[6];
  const float* dscale = (const float*)d_in[7];
  const float* W1 = (const float*)d_in[8];
  const float* b1 = (const float*)d_in[9];
  const float* W2 = (const float*)d_in[10];
  const float* b2 = (const float*)d_in[11];
  const float* g1 = (const float*)d_in[12];
  const float* be1 = (const float*)d_in[13];
  const float* g2 = (const float*)d_in[14];
  const float* be2 = (const float*)d_in[15];
  float* out = (float*)d_out;

  // workspace layout (bytes), ~98 MB max (proven safe):
  //   0         tok_bf 8MB
  //   8388608   wqkvT 1.5MB
  //   9961472   w1T   2MB
  //   12058624  w2T   2MB
  //   14155776  qbuf 8MB   \
  //   22544384  kbuf 8MB    } hbuf (32MB) overlays 14155776..47710208 after LN1
  //   30932992  vtbuf 8MB  /
  //   39321600  attnb 16.8MB (fp32 PV sums via atomics; zeroed at start; dead after LN1)
  //   56098816  Pbuf 32MB (per-batch, reused) -> xf/xbf/ybuf overlay after attention
  //   89653248  lbuf 2*4096 f32 — INSIDE ybuf range! lbuf dead after LN1; ybuf
  //             memset+writes happen strictly after LN1 (this ordering is the
  //             Round-7 NaN fix: memset(ybuf) before LN1 zeroed lbuf).
  char* ws = (char*)d_ws;
  u16*   tok_bf = (u16*)(ws + 0);
  u16*   wqkvT  = (u16*)(ws + 8388608);
  u16*   w1T    = (u16*)(ws + 9961472);
  u16*   w2T    = (u16*)(ws + 12058624);
  u16*   qbuf   = (u16*)(ws + 14155776);
  u16*   kbuf   = (u16*)(ws + 22544384);
  u16*   vtbuf  = (u16*)(ws + 30932992);
  float* attnb  = (float*)(ws + 39321600);   // ..56098816
  u16*   Pbuf   = (u16*)(ws + 56098816);     // ..89653248 (dead after pv(b=1))
  float* xf     = (float*)(ws + 56098816);   // ..72876032 (overlays Pbuf)
  u16*   xbf    = (u16*)(ws + 72876032);     // ..81264640 (overlays Pbuf)
  float* ybuf   = (float*)(ws + 81264640);   // ..98041856 (overlays Pbuf tail + lbuf)
  u16*   hbuf   = (u16*)(ws + 14155776);     // 32MB: ..47710208 (q/k/vt/attnb head; dead by ffn1)
  float* lbuf   = (float*)(ws + 89653248);

  (void)hipMemsetAsync(lbuf, 0, 2 * 4096 * sizeof(float), stream);
  (void)hipMemsetAsync(attnb, 0, (size_t)8192 * 512 * sizeof(float), stream);

  cast_bf_kernel<<<2048, 256, 0, stream>>>(tokens, tok_bf);
  transpose_qkv_kernel<<<dim3(16, 16, 3), 256, 0, stream>>>(Wq, Wk, Wv, wqkvT);
  transpose_bf_kernel<<<dim3(64, 16), 256, 0, stream>>>(W1, w1T, 512, 2048);
  transpose_bf_kernel<<<dim3(16, 64), 256, 0, stream>>>(W2, w2T, 2048, 512);

  gemm_qkv<<<dim3(12, 64), 256, 0, stream>>>(tok_bf, wqkvT, bq, bk, bv, qbuf, kbuf, vtbuf);

  // attention: two GEMM passes per batch (P buffer reused across batches)
  for (int b = 0; b < 2; ++b) {
    const u16* qb = qbuf + (size_t)b * 4096 * 512;
    const u16* kb = kbuf + (size_t)b * 4096 * 512;
    const u16* vb = vtbuf + (size_t)b * 512 * 4096;
    gemm_qk_p<<<528, 256, 0, stream>>>(qb, kb, dscale, Pbuf, lbuf + b * 4096);
    gemm_pv<<<dim3(4, 144), 256, 0, stream>>>(Pbuf, vb, attnb + (size_t)b * 4096 * 512);
  }

  ln1_kernel<<<2048, 256, 0, stream>>>(attnb, lbuf, tokens, g1, be1, xf, xbf);

  // ybuf overlaps lbuf (dead after LN1) and Pbuf tail (dead after attention):
  // zero it only AFTER ln1 has consumed lbuf.
  (void)hipMemsetAsync(ybuf, 0, (size_t)8192 * 512 * sizeof(float), stream);

  gemm_ffn1<<<dim3(16, 64), 256, 0, stream>>>(xbf, w1T, b1, hbuf);

  gemm_ffn2<<<dim3(4, 64, 4), 256, 0, stream>>>(hbuf, w2T, ybuf);

  ln2_kernel<<<2048, 256, 0, stream>>>(ybuf, b2, xf, g2, be2, out);
}

// Round 9
// 352.211 us; speedup vs baseline: 1.1576x; 1.1576x over previous
//
#include <hip/hip_runtime.h>
#include <hip/hip_bf16.h>
#include <math.h>

typedef unsigned short u16;
typedef __attribute__((ext_vector_type(8))) short short8;
typedef __attribute__((ext_vector_type(4))) float float4v;

#define MFMA_BF16(a, b, c) __builtin_amdgcn_mfma_f32_16x16x32_bf16((a), (b), (c), 0, 0, 0)

typedef const __attribute__((address_space(1))) void* gas_ptr;
typedef __attribute__((address_space(3))) void* las_ptr;

__device__ __forceinline__ u16 f2bf(float f) {
  __hip_bfloat16 h = __float2bfloat16(f);
  return __builtin_bit_cast(u16, h);
}

__device__ __forceinline__ float bf2f(u16 v) {
  return __builtin_bit_cast(float, (unsigned)v << 16);
}

__device__ __forceinline__ void load_lds16(const u16* g, u16* l) {
  __builtin_amdgcn_global_load_lds((gas_ptr)g, (las_ptr)l, 16, 0, 0);
}

// ---------------------------------------------------------------------------
// m97-style gemm_bt mainloop with general strides and K-window:
//   C[128x128] += A[m0.., kb..kend) * Bt[n0.., kb..kend)^T
// ---------------------------------------------------------------------------
__device__ __forceinline__ void gemm_mainloop(
    const u16* __restrict__ A, const u16* __restrict__ Bt,
    int kb, int kend, int lda, int ldb,
    int m0, int n0, u16* As, u16* Bs, float4v acc[4][4])
{
  const int tid = threadIdx.x;
  const int w = tid >> 6, lane = tid & 63;
  const int wr = w >> 1, wc = w & 1;
  const int lr = lane & 15, lk = (lane >> 4) * 8;
  for (int k0 = kb; k0 < kend; k0 += 32) {
#pragma unroll
    for (int c = 0; c < 2; ++c) {
      int idx = c * 256 + w * 64 + lane;
      int r = idx >> 2, c8 = idx & 3;
      load_lds16(A + (size_t)(m0 + r) * lda + k0 + c8 * 8, As + (size_t)(c * 256 + w * 64) * 8);
      load_lds16(Bt + (size_t)(n0 + r) * ldb + k0 + c8 * 8, Bs + (size_t)(c * 256 + w * 64) * 8);
    }
    __syncthreads();
    short8 af[4], bf[4];
#pragma unroll
    for (int mt = 0; mt < 4; ++mt)
      af[mt] = *(const short8*)&As[(wr * 64 + mt * 16 + lr) * 32 + lk];
#pragma unroll
    for (int nt = 0; nt < 4; ++nt)
      bf[nt] = *(const short8*)&Bs[(wc * 64 + nt * 16 + lr) * 32 + lk];
#pragma unroll
    for (int mt = 0; mt < 4; ++mt)
#pragma unroll
      for (int nt = 0; nt < 4; ++nt)
        acc[mt][nt] = MFMA_BF16(af[mt], bf[nt], acc[mt][nt]);
    __syncthreads();
  }
}

// ---------------------------------------------------------------------------
// GEMM 1: QKV projection
// ---------------------------------------------------------------------------
__global__ __launch_bounds__(256) void gemm_qkv(
    const u16* __restrict__ A, const u16* __restrict__ Bt,
    const float* __restrict__ bq, const float* __restrict__ bk, const float* __restrict__ bv,
    u16* __restrict__ qo, u16* __restrict__ ko, u16* __restrict__ vto)
{
  __shared__ u16 As[128 * 32], Bs[128 * 32];
  float4v acc[4][4];
#pragma unroll
  for (int mt = 0; mt < 4; ++mt)
#pragma unroll
    for (int nt = 0; nt < 4; ++nt) acc[mt][nt] = (float4v){0.f, 0.f, 0.f, 0.f};
  const int m0 = blockIdx.y * 128, n0 = blockIdx.x * 128;
  gemm_mainloop(A, Bt, 0, 512, 512, 512, m0, n0, As, Bs, acc);
  const int tid = threadIdx.x, w = tid >> 6, lane = tid & 63;
  const int wr = w >> 1, wc = w & 1, lr = lane & 15, lg = lane >> 4;
#pragma unroll
  for (int mt = 0; mt < 4; ++mt) {
#pragma unroll
    for (int nt = 0; nt < 4; ++nt) {
      int n = n0 + wc * 64 + nt * 16 + lr;
#pragma unroll
      for (int r = 0; r < 4; ++r) {
        int i = m0 + wr * 64 + mt * 16 + lg * 4 + r;
        float v = acc[mt][nt][r];
        if (n < 512) {
          qo[(size_t)i * 512 + n] = f2bf(v + bq[n]);
        } else if (n < 1024) {
          ko[(size_t)i * 512 + (n - 512)] = f2bf(v + bk[n - 512]);
        } else {
          int bb = i >> 12, t = i & 4095;
          vto[((size_t)(bb * 512 + (n - 1024))) * 4096 + t] = f2bf(v + bv[n - 1024]);
        }
      }
    }
  }
}

// ---------------------------------------------------------------------------
// Attention pass 1: P = exp(QK^T/sqrt(d) - ds*dist), causal, bf16 out.
// One batch per launch. Triangular tile grid (528 blocks). Row sums -> l
// via float atomics (l zeroed before; only ~270k atomics, negligible).
// ---------------------------------------------------------------------------
__global__ __launch_bounds__(256) void gemm_qk_p(
    const u16* __restrict__ q, const u16* __restrict__ k,
    const float* __restrict__ dsp,
    u16* __restrict__ P, float* __restrict__ l)
{
  __shared__ u16 As[128 * 32], Bs[128 * 32];
  float4v acc[4][4];
#pragma unroll
  for (int mt = 0; mt < 4; ++mt)
#pragma unroll
    for (int nt = 0; nt < 4; ++nt) acc[mt][nt] = (float4v){0.f, 0.f, 0.f, 0.f};
  int idx = blockIdx.x;
  int tm = (int)((sqrtf(8.0f * (float)idx + 1.0f) - 1.0f) * 0.5f);
  while ((tm + 1) * (tm + 2) / 2 <= idx) ++tm;
  while (tm * (tm + 1) / 2 > idx) --tm;
  int tn = idx - tm * (tm + 1) / 2;
  const int m0 = tm * 128, n0 = tn * 128;
  gemm_mainloop(q, k, 0, 512, 512, 512, m0, n0, As, Bs, acc);
  const int tid = threadIdx.x, w = tid >> 6, lane = tid & 63;
  const int wr = w >> 1, wc = w & 1, lr = lane & 15, lg = lane >> 4;
  const float invs = 0.04419417382415922f;   // 1/sqrt(512)
  const float dsi = dsp[0] * invs;
  const float L2E = 1.4426950408889634f;
  float rs[4][4];
#pragma unroll
  for (int mt = 0; mt < 4; ++mt)
#pragma unroll
    for (int r = 0; r < 4; ++r) rs[mt][r] = 0.f;
#pragma unroll
  for (int mt = 0; mt < 4; ++mt) {
#pragma unroll
    for (int nt = 0; nt < 4; ++nt) {
      int j = n0 + wc * 64 + nt * 16 + lr;
#pragma unroll
      for (int r = 0; r < 4; ++r) {
        int i = m0 + wr * 64 + mt * 16 + lg * 4 + r;
        float x = acc[mt][nt][r] * invs - dsi * fabsf((float)(i - j));
        float p = (j > i) ? 0.f : exp2f(x * L2E);
        P[(size_t)i * 4096 + j] = f2bf(p);
        rs[mt][r] += p;
      }
    }
  }
#pragma unroll
  for (int mt = 0; mt < 4; ++mt) {
#pragma unroll
    for (int r = 0; r < 4; ++r) {
      float v = rs[mt][r];
#pragma unroll
      for (int off = 1; off < 16; off <<= 1) v += __shfl_xor(v, off, 64);
      if (lr == 0)
        atomicAdd(&l[m0 + wr * 64 + mt * 16 + lg * 4 + r], v);
    }
  }
}

// ---------------------------------------------------------------------------
// Attention pass 2: of += P @ V, K-chunks of <=1024 elems (32 iters).
// chunks per tm = (tm>>3)+1, total pairs = 80; grid (4, 80).
// atomicAdd into zeroed of: 5.2M atomics/launch, <=4 contenders/address.
// ---------------------------------------------------------------------------
__global__ __launch_bounds__(256) void gemm_pv(
    const u16* __restrict__ P, const u16* __restrict__ vt,
    float* __restrict__ of)
{
  __shared__ u16 As[128 * 32], Bs[128 * 32];
  float4v acc[4][4];
#pragma unroll
  for (int mt = 0; mt < 4; ++mt)
#pragma unroll
    for (int nt = 0; nt < 4; ++nt) acc[mt][nt] = (float4v){0.f, 0.f, 0.f, 0.f};
  // decode (tm, chunk) from blockIdx.y: chunks per tm = (tm>>3)+1
  int rem = blockIdx.y;
  int tm = 0, cpt = 1;
  while (rem >= cpt) { rem -= cpt; ++tm; cpt = (tm >> 3) + 1; }
  const int m0 = tm * 128, n0 = blockIdx.x * 128;
  const int kb = rem * 1024;
  const int kfull = (tm + 1) * 128;
  const int kend = (kb + 1024 < kfull) ? (kb + 1024) : kfull;
  gemm_mainloop(P, vt, kb, kend, 4096, 4096, m0, n0, As, Bs, acc);
  const int tid = threadIdx.x, w = tid >> 6, lane = tid & 63;
  const int wr = w >> 1, wc = w & 1, lr = lane & 15, lg = lane >> 4;
#pragma unroll
  for (int mt = 0; mt < 4; ++mt) {
#pragma unroll
    for (int nt = 0; nt < 4; ++nt) {
      int n = n0 + wc * 64 + nt * 16 + lr;
#pragma unroll
      for (int r = 0; r < 4; ++r) {
        int i = m0 + wr * 64 + mt * 16 + lg * 4 + r;
        atomicAdd(&of[(size_t)i * 512 + n], acc[mt][nt][r]);
      }
    }
  }
}

// ---------------------------------------------------------------------------
// GEMM: FFN1 (relu epilogue)
// ---------------------------------------------------------------------------
__global__ __launch_bounds__(256) void gemm_ffn1(
    const u16* __restrict__ A, const u16* __restrict__ Bt,
    const float* __restrict__ b1, u16* __restrict__ h)
{
  __shared__ u16 As[128 * 32], Bs[128 * 32];
  float4v acc[4][4];
#pragma unroll
  for (int mt = 0; mt < 4; ++mt)
#pragma unroll
    for (int nt = 0; nt < 4; ++nt) acc[mt][nt] = (float4v){0.f, 0.f, 0.f, 0.f};
  const int m0 = blockIdx.y * 128, n0 = blockIdx.x * 128;
  gemm_mainloop(A, Bt, 0, 512, 512, 512, m0, n0, As, Bs, acc);
  const int tid = threadIdx.x, w = tid >> 6, lane = tid & 63;
  const int wr = w >> 1, wc = w & 1, lr = lane & 15, lg = lane >> 4;
#pragma unroll
  for (int mt = 0; mt < 4; ++mt) {
#pragma unroll
    for (int nt = 0; nt < 4; ++nt) {
      int n = n0 + wc * 64 + nt * 16 + lr;
#pragma unroll
      for (int r = 0; r < 4; ++r) {
        int i = m0 + wr * 64 + mt * 16 + lg * 4 + r;
        h[(size_t)i * 2048 + n] = f2bf(fmaxf(acc[mt][nt][r] + b1[n], 0.f));
      }
    }
  }
}

// ---------------------------------------------------------------------------
// GEMM: FFN2, K=2048 split x2 (32 iters/block), NO atomics:
//   z=0: k in [0,1024)    -> plain fp32 store to y0
//   z=1: k in [1024,2048) -> plain bf16 store to y1
// LN2 computes y0 + y1 + b2 + x.
// ---------------------------------------------------------------------------
__global__ __launch_bounds__(256) void gemm_ffn2(
    const u16* __restrict__ A, const u16* __restrict__ Bt,
    float* __restrict__ y0, u16* __restrict__ y1)
{
  __shared__ u16 As[128 * 32], Bs[128 * 32];
  float4v acc[4][4];
#pragma unroll
  for (int mt = 0; mt < 4; ++mt)
#pragma unroll
    for (int nt = 0; nt < 4; ++nt) acc[mt][nt] = (float4v){0.f, 0.f, 0.f, 0.f};
  const int m0 = blockIdx.y * 128, n0 = blockIdx.x * 128;
  const int kb = blockIdx.z * 1024;
  gemm_mainloop(A, Bt, kb, kb + 1024, 2048, 2048, m0, n0, As, Bs, acc);
  const int tid = threadIdx.x, w = tid >> 6, lane = tid & 63;
  const int wr = w >> 1, wc = w & 1, lr = lane & 15, lg = lane >> 4;
#pragma unroll
  for (int mt = 0; mt < 4; ++mt) {
#pragma unroll
    for (int nt = 0; nt < 4; ++nt) {
      int n = n0 + wc * 64 + nt * 16 + lr;
#pragma unroll
      for (int r = 0; r < 4; ++r) {
        int i = m0 + wr * 64 + mt * 16 + lg * 4 + r;
        if (blockIdx.z == 0) y0[(size_t)i * 512 + n] = acc[mt][nt][r];
        else                 y1[(size_t)i * 512 + n] = f2bf(acc[mt][nt][r]);
      }
    }
  }
}

// ---------------------------------------------------------------------------
// LN1: x = LN(attn/l + tokens); writes fp32 + bf16
// ---------------------------------------------------------------------------
__global__ __launch_bounds__(256) void ln1_kernel(
    const float* __restrict__ a, const float* __restrict__ lsum,
    const float* __restrict__ tok,
    const float* __restrict__ g, const float* __restrict__ be,
    float* __restrict__ of, u16* __restrict__ ob)
{
  const int row = blockIdx.x * 4 + (threadIdx.x >> 6);
  const int lane = threadIdx.x & 63;
  const size_t base = (size_t)row * 512 + lane * 8;
  const float linv = 1.0f / lsum[row];
  float v[8];
#pragma unroll
  for (int t = 0; t < 8; ++t)
    v[t] = a[base + t] * linv + tok[base + t];
  float s = 0.f;
#pragma unroll
  for (int t = 0; t < 8; ++t) s += v[t];
#pragma unroll
  for (int off = 1; off < 64; off <<= 1) s += __shfl_xor(s, off, 64);
  const float mu = s * (1.0f / 512.0f);
  float qv = 0.f;
#pragma unroll
  for (int t = 0; t < 8; ++t) { float d = v[t] - mu; qv += d * d; }
#pragma unroll
  for (int off = 1; off < 64; off <<= 1) qv += __shfl_xor(qv, off, 64);
  const float rs = rsqrtf(qv * (1.0f / 512.0f) + 1e-5f);
  const int cb = lane * 8;
#pragma unroll
  for (int t = 0; t < 8; ++t) {
    float xv = (v[t] - mu) * rs * g[cb + t] + be[cb + t];
    of[base + t] = xv;
    ob[base + t] = f2bf(xv);
  }
}

// ---------------------------------------------------------------------------
// LN2: out = LN(y0 + y1 + b2 + x)
// ---------------------------------------------------------------------------
__global__ __launch_bounds__(256) void ln2_kernel(
    const float* __restrict__ y0, const u16* __restrict__ y1,
    const float* __restrict__ b2, const float* __restrict__ bsrc,
    const float* __restrict__ g, const float* __restrict__ be,
    float* __restrict__ of)
{
  const int row = blockIdx.x * 4 + (threadIdx.x >> 6);
  const int lane = threadIdx.x & 63;
  const size_t base = (size_t)row * 512 + lane * 8;
  const int cb = lane * 8;
  float v[8];
#pragma unroll
  for (int t = 0; t < 8; ++t)
    v[t] = y0[base + t] + bf2f(y1[base + t]) + b2[cb + t] + bsrc[base + t];
  float s = 0.f;
#pragma unroll
  for (int t = 0; t < 8; ++t) s += v[t];
#pragma unroll
  for (int off = 1; off < 64; off <<= 1) s += __shfl_xor(s, off, 64);
  const float mu = s * (1.0f / 512.0f);
  float qv = 0.f;
#pragma unroll
  for (int t = 0; t < 8; ++t) { float d = v[t] - mu; qv += d * d; }
#pragma unroll
  for (int off = 1; off < 64; off <<= 1) qv += __shfl_xor(qv, off, 64);
  const float rs = rsqrtf(qv * (1.0f / 512.0f) + 1e-5f);
#pragma unroll
  for (int t = 0; t < 8; ++t) {
    float xv = (v[t] - mu) * rs * g[cb + t] + be[cb + t];
    of[base + t] = xv;
  }
}

// ---------------------------------------------------------------------------
// prep kernels
// ---------------------------------------------------------------------------
__global__ __launch_bounds__(256) void cast_bf_kernel(
    const float* __restrict__ in, u16* __restrict__ out)
{
  const size_t i = ((size_t)blockIdx.x * 256 + threadIdx.x) * 8;
#pragma unroll
  for (int t = 0; t < 8; ++t) out[i + t] = f2bf(in[i + t]);
}

// Tiled transpose for the three 512x512 QKV weights in one launch (z = which).
__global__ __launch_bounds__(256) void transpose_qkv_kernel(
    const float* __restrict__ Wq, const float* __restrict__ Wk,
    const float* __restrict__ Wv, u16* __restrict__ dst)
{
  __shared__ u16 tile[32][33];
  const float* src = (blockIdx.z == 0) ? Wq : (blockIdx.z == 1) ? Wk : Wv;
  u16* d = dst + (size_t)blockIdx.z * 512 * 512;
  const int tx = threadIdx.x & 31, ty = threadIdx.x >> 5;
  const int n0 = blockIdx.x * 32, k0 = blockIdx.y * 32;
#pragma unroll
  for (int i = 0; i < 32; i += 8)
    tile[ty + i][tx] = f2bf(src[(size_t)(k0 + ty + i) * 512 + n0 + tx]);
  __syncthreads();
#pragma unroll
  for (int i = 0; i < 32; i += 8)
    d[(size_t)(n0 + ty + i) * 512 + k0 + tx] = tile[tx][ty + i];
}

__global__ __launch_bounds__(256) void transpose_bf_kernel(
    const float* __restrict__ src, u16* __restrict__ dst, int K, int N)
{
  __shared__ u16 tile[32][33];
  const int tx = threadIdx.x & 31, ty = threadIdx.x >> 5;
  const int n0 = blockIdx.x * 32, k0 = blockIdx.y * 32;
#pragma unroll
  for (int i = 0; i < 32; i += 8)
    tile[ty + i][tx] = f2bf(src[(size_t)(k0 + ty + i) * N + n0 + tx]);
  __syncthreads();
#pragma unroll
  for (int i = 0; i < 32; i += 8)
    dst[(size_t)(n0 + ty + i) * K + k0 + tx] = tile[tx][ty + i];
}

// ---------------------------------------------------------------------------
// launch
// ---------------------------------------------------------------------------
extern "C" void kernel_launch(void* const* d_in, const int* in_sizes, int n_in,
                              void* d_out, int out_size, void* d_ws, size_t ws_size,
                              hipStream_t stream) {
  const float* tokens = (const float*)d_in[0];
  const float* Wq = (const float*)d_in[1];
  const float* bq = (const float*)d_in[2];
  const float* Wk = (const float*)d_in[3];
  const float* bk = (const float*)d_in[4];
  const float* Wv = (const float*)d_in[5];
  const float* bv = (const float*)d_in[6];
  const float* dscale = (const float*)d_in[7];
  const float* W1 = (const float*)d_in[8];
  const float* b1 = (const float*)d_in[9];
  const float* W2 = (const float*)d_in[10];
  const float* b2 = (const float*)d_in[11];
  const float* g1 = (const float*)d_in[12];
  const float* be1 = (const float*)d_in[13];
  const float* g2 = (const float*)d_in[14];
  const float* be2 = (const float*)d_in[15];
  float* out = (float*)d_out;

  // workspace map (bytes). Lifetimes:
  //   [0,8388608)        tok_bf (dead after qkv)           -> y1 (bf16, ffn2 z=1)
  //   [8388608,9961472)  wqkvT  (dead after qkv)
  //   [9961472,12058624) w1T    (live until ffn1)
  //   [12058624,14155776) w2T   (live until ffn2)
  //   [14155776,22544384) qbuf  (dead after qk_p b=1)  \
  //   [22544384,30932992) kbuf  (dead after qk_p b=1)   } -> xf (fp32, LN1 out)
  //   [30932992,39321600) vtbuf (dead after pv b=1)        -> xbf (bf16, LN1 out)
  //   [39321600,56098816) attnb (pv atomic target; dead after LN1) -> y0 (fp32)
  //   [56098816,89653248) Pbuf  (dead after pv b=1)        -> hbuf (32MB)
  //   [89653248,...)     lbuf 2*4096 f32 (dead after LN1)
  char* ws = (char*)d_ws;
  u16*   tok_bf = (u16*)(ws + 0);
  u16*   y1buf  = (u16*)(ws + 0);
  u16*   wqkvT  = (u16*)(ws + 8388608);
  u16*   w1T    = (u16*)(ws + 9961472);
  u16*   w2T    = (u16*)(ws + 12058624);
  u16*   qbuf   = (u16*)(ws + 14155776);
  u16*   kbuf   = (u16*)(ws + 22544384);
  u16*   vtbuf  = (u16*)(ws + 30932992);
  float* xf     = (float*)(ws + 14155776);   // overlays qbuf+kbuf (dead by LN1)
  u16*   xbf    = (u16*)(ws + 30932992);     // overlays vtbuf (dead by LN1)
  float* attnb  = (float*)(ws + 39321600);
  float* y0buf  = (float*)(ws + 39321600);   // overlays attnb (dead after LN1)
  u16*   Pbuf   = (u16*)(ws + 56098816);
  u16*   hbuf   = (u16*)(ws + 56098816);     // overlays Pbuf (dead after attention)
  float* lbuf   = (float*)(ws + 89653248);

  (void)hipMemsetAsync(lbuf, 0, 2 * 4096 * sizeof(float), stream);
  (void)hipMemsetAsync(attnb, 0, (size_t)8192 * 512 * sizeof(float), stream);

  cast_bf_kernel<<<2048, 256, 0, stream>>>(tokens, tok_bf);
  transpose_qkv_kernel<<<dim3(16, 16, 3), 256, 0, stream>>>(Wq, Wk, Wv, wqkvT);
  transpose_bf_kernel<<<dim3(64, 16), 256, 0, stream>>>(W1, w1T, 512, 2048);
  transpose_bf_kernel<<<dim3(16, 64), 256, 0, stream>>>(W2, w2T, 2048, 512);

  gemm_qkv<<<dim3(12, 64), 256, 0, stream>>>(tok_bf, wqkvT, bq, bk, bv, qbuf, kbuf, vtbuf);

  // attention: two GEMM passes per batch (P buffer reused across batches)
  for (int b = 0; b < 2; ++b) {
    const u16* qb = qbuf + (size_t)b * 4096 * 512;
    const u16* kb = kbuf + (size_t)b * 4096 * 512;
    const u16* vb = vtbuf + (size_t)b * 512 * 4096;
    gemm_qk_p<<<528, 256, 0, stream>>>(qb, kb, dscale, Pbuf, lbuf + b * 4096);
    gemm_pv<<<dim3(4, 80), 256, 0, stream>>>(Pbuf, vb, attnb + (size_t)b * 4096 * 512);
  }

  // LN1 consumes attnb + lbuf; writes xf (over q/k) and xbf (over vt)
  ln1_kernel<<<2048, 256, 0, stream>>>(attnb, lbuf, tokens, g1, be1, xf, xbf);

  gemm_ffn1<<<dim3(16, 64), 256, 0, stream>>>(xbf, w1T, b1, hbuf);

  gemm_ffn2<<<dim3(4, 64, 2), 256, 0, stream>>>(hbuf, w2T, y0buf, y1buf);

  ln2_kernel<<<2048, 256, 0, stream>>>(y0buf, y1buf, b2, xf, g2, be2, out);
}

// Round 11
// 326.169 us; speedup vs baseline: 1.2500x; 1.0798x over previous
//
#include <hip/hip_runtime.h>
#include <hip/hip_bf16.h>
#include <math.h>

typedef unsigned short u16;
typedef __attribute__((ext_vector_type(8))) short short8;
typedef __attribute__((ext_vector_type(4))) float float4v;

#define MFMA_BF16(a, b, c) __builtin_amdgcn_mfma_f32_16x16x32_bf16((a), (b), (c), 0, 0, 0)

typedef const __attribute__((address_space(1))) void* gas_ptr;
typedef __attribute__((address_space(3))) void* las_ptr;

__device__ __forceinline__ u16 f2bf(float f) {
  __hip_bfloat16 h = __float2bfloat16(f);
  return __builtin_bit_cast(u16, h);
}

__device__ __forceinline__ float bf2f(u16 v) {
  return __builtin_bit_cast(float, (unsigned)v << 16);
}

__device__ __forceinline__ void load_lds16(const u16* g, u16* l) {
  __builtin_amdgcn_global_load_lds((gas_ptr)g, (las_ptr)l, 16, 0, 0);
}

// ---------------------------------------------------------------------------
// m97-style gemm_bt mainloop with general strides and K-window:
//   C[128x128] += A[m0.., kb..kend) * Bt[n0.., kb..kend)^T
// ---------------------------------------------------------------------------
__device__ __forceinline__ void gemm_mainloop(
    const u16* __restrict__ A, const u16* __restrict__ Bt,
    int kb, int kend, int lda, int ldb,
    int m0, int n0, u16* As, u16* Bs, float4v acc[4][4])
{
  const int tid = threadIdx.x;
  const int w = tid >> 6, lane = tid & 63;
  const int wr = w >> 1, wc = w & 1;
  const int lr = lane & 15, lk = (lane >> 4) * 8;
  for (int k0 = kb; k0 < kend; k0 += 32) {
#pragma unroll
    for (int c = 0; c < 2; ++c) {
      int idx = c * 256 + w * 64 + lane;
      int r = idx >> 2, c8 = idx & 3;
      load_lds16(A + (size_t)(m0 + r) * lda + k0 + c8 * 8, As + (size_t)(c * 256 + w * 64) * 8);
      load_lds16(Bt + (size_t)(n0 + r) * ldb + k0 + c8 * 8, Bs + (size_t)(c * 256 + w * 64) * 8);
    }
    __syncthreads();
    short8 af[4], bf[4];
#pragma unroll
    for (int mt = 0; mt < 4; ++mt)
      af[mt] = *(const short8*)&As[(wr * 64 + mt * 16 + lr) * 32 + lk];
#pragma unroll
    for (int nt = 0; nt < 4; ++nt)
      bf[nt] = *(const short8*)&Bs[(wc * 64 + nt * 16 + lr) * 32 + lk];
#pragma unroll
    for (int mt = 0; mt < 4; ++mt)
#pragma unroll
      for (int nt = 0; nt < 4; ++nt)
        acc[mt][nt] = MFMA_BF16(af[mt], bf[nt], acc[mt][nt]);
    __syncthreads();
  }
}

// ---------------------------------------------------------------------------
// GEMM 1: QKV projection
// ---------------------------------------------------------------------------
__global__ __launch_bounds__(256) void gemm_qkv(
    const u16* __restrict__ A, const u16* __restrict__ Bt,
    const float* __restrict__ bq, const float* __restrict__ bk, const float* __restrict__ bv,
    u16* __restrict__ qo, u16* __restrict__ ko, u16* __restrict__ vto)
{
  __shared__ u16 As[128 * 32], Bs[128 * 32];
  float4v acc[4][4];
#pragma unroll
  for (int mt = 0; mt < 4; ++mt)
#pragma unroll
    for (int nt = 0; nt < 4; ++nt) acc[mt][nt] = (float4v){0.f, 0.f, 0.f, 0.f};
  const int m0 = blockIdx.y * 128, n0 = blockIdx.x * 128;
  gemm_mainloop(A, Bt, 0, 512, 512, 512, m0, n0, As, Bs, acc);
  const int tid = threadIdx.x, w = tid >> 6, lane = tid & 63;
  const int wr = w >> 1, wc = w & 1, lr = lane & 15, lg = lane >> 4;
#pragma unroll
  for (int mt = 0; mt < 4; ++mt) {
#pragma unroll
    for (int nt = 0; nt < 4; ++nt) {
      int n = n0 + wc * 64 + nt * 16 + lr;
#pragma unroll
      for (int r = 0; r < 4; ++r) {
        int i = m0 + wr * 64 + mt * 16 + lg * 4 + r;
        float v = acc[mt][nt][r];
        if (n < 512) {
          qo[(size_t)i * 512 + n] = f2bf(v + bq[n]);
        } else if (n < 1024) {
          ko[(size_t)i * 512 + (n - 512)] = f2bf(v + bk[n - 512]);
        } else {
          int bb = i >> 12, t = i & 4095;
          vto[((size_t)(bb * 512 + (n - 1024))) * 4096 + t] = f2bf(v + bv[n - 1024]);
        }
      }
    }
  }
}

// ---------------------------------------------------------------------------
// Attention pass 1: P = exp(QK^T/sqrt(d) - ds*dist), causal, bf16 out.
// Both batches in one launch (blockIdx.y = batch). Triangular tile grid
// (528 x-blocks). Row sums -> l via float atomics (~270k, negligible).
// ---------------------------------------------------------------------------
__global__ __launch_bounds__(256) void gemm_qk_p(
    const u16* __restrict__ q, const u16* __restrict__ k,
    const float* __restrict__ dsp,
    u16* __restrict__ P, float* __restrict__ l)
{
  __shared__ u16 As[128 * 32], Bs[128 * 32];
  float4v acc[4][4];
#pragma unroll
  for (int mt = 0; mt < 4; ++mt)
#pragma unroll
    for (int nt = 0; nt < 4; ++nt) acc[mt][nt] = (float4v){0.f, 0.f, 0.f, 0.f};
  const int b = blockIdx.y;
  const u16* qb = q + (size_t)b * 4096 * 512;
  const u16* kb = k + (size_t)b * 4096 * 512;
  u16* Pb = P + (size_t)b * 4096 * 4096;
  float* lb = l + b * 4096;
  int idx = blockIdx.x;
  int tm = (int)((sqrtf(8.0f * (float)idx + 1.0f) - 1.0f) * 0.5f);
  while ((tm + 1) * (tm + 2) / 2 <= idx) ++tm;
  while (tm * (tm + 1) / 2 > idx) --tm;
  int tn = idx - tm * (tm + 1) / 2;
  const int m0 = tm * 128, n0 = tn * 128;
  gemm_mainloop(qb, kb, 0, 512, 512, 512, m0, n0, As, Bs, acc);
  const int tid = threadIdx.x, w = tid >> 6, lane = tid & 63;
  const int wr = w >> 1, wc = w & 1, lr = lane & 15, lg = lane >> 4;
  const float invs = 0.04419417382415922f;   // 1/sqrt(512)
  const float dsi = dsp[0] * invs;
  const float L2E = 1.4426950408889634f;
  float rs[4][4];
#pragma unroll
  for (int mt = 0; mt < 4; ++mt)
#pragma unroll
    for (int r = 0; r < 4; ++r) rs[mt][r] = 0.f;
#pragma unroll
  for (int mt = 0; mt < 4; ++mt) {
#pragma unroll
    for (int nt = 0; nt < 4; ++nt) {
      int j = n0 + wc * 64 + nt * 16 + lr;
#pragma unroll
      for (int r = 0; r < 4; ++r) {
        int i = m0 + wr * 64 + mt * 16 + lg * 4 + r;
        float x = acc[mt][nt][r] * invs - dsi * fabsf((float)(i - j));
        float p = (j > i) ? 0.f : exp2f(x * L2E);
        Pb[(size_t)i * 4096 + j] = f2bf(p);
        rs[mt][r] += p;
      }
    }
  }
#pragma unroll
  for (int mt = 0; mt < 4; ++mt) {
#pragma unroll
    for (int r = 0; r < 4; ++r) {
      float v = rs[mt][r];
#pragma unroll
      for (int off = 1; off < 16; off <<= 1) v += __shfl_xor(v, off, 64);
      if (lr == 0)
        atomicAdd(&lb[m0 + wr * 64 + mt * 16 + lg * 4 + r], v);
    }
  }
}

// ---------------------------------------------------------------------------
// Attention pass 2: P @ V with K-chunks of <=1024 elems (<=32 iters).
// chunks per tm = (tm>>3)+1 (max 4), total (tm,chunk) pairs = 80.
// Grid (4, 80, 2); blockIdx.z = batch. NO atomics:
//   chunk 0 -> y0 fp32 plain store (every tile-row has chunk 0)
//   chunk c>=1 -> y1/y2/y3 bf16 plain store (those buffers pre-zeroed).
// LN1 computes (y0+y1+y2+y3)/l + tok.
// ---------------------------------------------------------------------------
__global__ __launch_bounds__(256) void gemm_pv(
    const u16* __restrict__ P, const u16* __restrict__ vt,
    float* __restrict__ y0, u16* __restrict__ y1,
    u16* __restrict__ y2, u16* __restrict__ y3)
{
  __shared__ u16 As[128 * 32], Bs[128 * 32];
  float4v acc[4][4];
#pragma unroll
  for (int mt = 0; mt < 4; ++mt)
#pragma unroll
    for (int nt = 0; nt < 4; ++nt) acc[mt][nt] = (float4v){0.f, 0.f, 0.f, 0.f};
  const int b = blockIdx.z;
  const u16* Pb = P + (size_t)b * 4096 * 4096;
  const u16* vb = vt + (size_t)b * 512 * 4096;
  // decode (tm, chunk): chunks per tm = (tm>>3)+1
  int rem = blockIdx.y;
  int tm = 0, cpt = 1;
  while (rem >= cpt) { rem -= cpt; ++tm; cpt = (tm >> 3) + 1; }
  const int m0 = tm * 128, n0 = blockIdx.x * 128;
  const int kb = rem * 1024;
  const int kfull = (tm + 1) * 128;
  const int kend = (kb + 1024 < kfull) ? (kb + 1024) : kfull;
  gemm_mainloop(Pb, vb, kb, kend, 4096, 4096, m0, n0, As, Bs, acc);
  const int tid = threadIdx.x, w = tid >> 6, lane = tid & 63;
  const int wr = w >> 1, wc = w & 1, lr = lane & 15, lg = lane >> 4;
  const size_t bofs = (size_t)b * 4096 * 512;
#pragma unroll
  for (int mt = 0; mt < 4; ++mt) {
#pragma unroll
    for (int nt = 0; nt < 4; ++nt) {
      int n = n0 + wc * 64 + nt * 16 + lr;
#pragma unroll
      for (int r = 0; r < 4; ++r) {
        int i = m0 + wr * 64 + mt * 16 + lg * 4 + r;
        size_t o = bofs + (size_t)i * 512 + n;
        float v = acc[mt][nt][r];
        if (rem == 0)      y0[o] = v;
        else if (rem == 1) y1[o] = f2bf(v);
        else if (rem == 2) y2[o] = f2bf(v);
        else               y3[o] = f2bf(v);
      }
    }
  }
}

// ---------------------------------------------------------------------------
// GEMM: FFN1 (relu epilogue)
// ---------------------------------------------------------------------------
__global__ __launch_bounds__(256) void gemm_ffn1(
    const u16* __restrict__ A, const u16* __restrict__ Bt,
    const float* __restrict__ b1, u16* __restrict__ h)
{
  __shared__ u16 As[128 * 32], Bs[128 * 32];
  float4v acc[4][4];
#pragma unroll
  for (int mt = 0; mt < 4; ++mt)
#pragma unroll
    for (int nt = 0; nt < 4; ++nt) acc[mt][nt] = (float4v){0.f, 0.f, 0.f, 0.f};
  const int m0 = blockIdx.y * 128, n0 = blockIdx.x * 128;
  gemm_mainloop(A, Bt, 0, 512, 512, 512, m0, n0, As, Bs, acc);
  const int tid = threadIdx.x, w = tid >> 6, lane = tid & 63;
  const int wr = w >> 1, wc = w & 1, lr = lane & 15, lg = lane >> 4;
#pragma unroll
  for (int mt = 0; mt < 4; ++mt) {
#pragma unroll
    for (int nt = 0; nt < 4; ++nt) {
      int n = n0 + wc * 64 + nt * 16 + lr;
#pragma unroll
      for (int r = 0; r < 4; ++r) {
        int i = m0 + wr * 64 + mt * 16 + lg * 4 + r;
        h[(size_t)i * 2048 + n] = f2bf(fmaxf(acc[mt][nt][r] + b1[n], 0.f));
      }
    }
  }
}

// ---------------------------------------------------------------------------
// GEMM: FFN2, K=2048 split x2 (32 iters/block), NO atomics:
//   z=0 -> fp32 store to f0 ; z=1 -> bf16 store to f1. LN2 sums.
// ---------------------------------------------------------------------------
__global__ __launch_bounds__(256) void gemm_ffn2(
    const u16* __restrict__ A, const u16* __restrict__ Bt,
    float* __restrict__ f0, u16* __restrict__ f1)
{
  __shared__ u16 As[128 * 32], Bs[128 * 32];
  float4v acc[4][4];
#pragma unroll
  for (int mt = 0; mt < 4; ++mt)
#pragma unroll
    for (int nt = 0; nt < 4; ++nt) acc[mt][nt] = (float4v){0.f, 0.f, 0.f, 0.f};
  const int m0 = blockIdx.y * 128, n0 = blockIdx.x * 128;
  const int kb = blockIdx.z * 1024;
  gemm_mainloop(A, Bt, kb, kb + 1024, 2048, 2048, m0, n0, As, Bs, acc);
  const int tid = threadIdx.x, w = tid >> 6, lane = tid & 63;
  const int wr = w >> 1, wc = w & 1, lr = lane & 15, lg = lane >> 4;
#pragma unroll
  for (int mt = 0; mt < 4; ++mt) {
#pragma unroll
    for (int nt = 0; nt < 4; ++nt) {
      int n = n0 + wc * 64 + nt * 16 + lr;
#pragma unroll
      for (int r = 0; r < 4; ++r) {
        int i = m0 + wr * 64 + mt * 16 + lg * 4 + r;
        if (blockIdx.z == 0) f0[(size_t)i * 512 + n] = acc[mt][nt][r];
        else                 f1[(size_t)i * 512 + n] = f2bf(acc[mt][nt][r]);
      }
    }
  }
}

// ---------------------------------------------------------------------------
// LN1: x = LN((y0+y1+y2+y3)/l + tokens); writes fp32 + bf16
// ---------------------------------------------------------------------------
__global__ __launch_bounds__(256) void ln1_kernel(
    const float* __restrict__ y0, const u16* __restrict__ y1,
    const u16* __restrict__ y2, const u16* __restrict__ y3,
    const float* __restrict__ lsum, const float* __restrict__ tok,
    const float* __restrict__ g, const float* __restrict__ be,
    float* __restrict__ of, u16* __restrict__ ob)
{
  const int row = blockIdx.x * 4 + (threadIdx.x >> 6);
  const int lane = threadIdx.x & 63;
  const size_t base = (size_t)row * 512 + lane * 8;
  const float linv = 1.0f / lsum[row];
  float v[8];
#pragma unroll
  for (int t = 0; t < 8; ++t) {
    float a = y0[base + t] + bf2f(y1[base + t]) + bf2f(y2[base + t]) + bf2f(y3[base + t]);
    v[t] = a * linv + tok[base + t];
  }
  float s = 0.f;
#pragma unroll
  for (int t = 0; t < 8; ++t) s += v[t];
#pragma unroll
  for (int off = 1; off < 64; off <<= 1) s += __shfl_xor(s, off, 64);
  const float mu = s * (1.0f / 512.0f);
  float qv = 0.f;
#pragma unroll
  for (int t = 0; t < 8; ++t) { float d = v[t] - mu; qv += d * d; }
#pragma unroll
  for (int off = 1; off < 64; off <<= 1) qv += __shfl_xor(qv, off, 64);
  const float rs = rsqrtf(qv * (1.0f / 512.0f) + 1e-5f);
  const int cb = lane * 8;
#pragma unroll
  for (int t = 0; t < 8; ++t) {
    float xv = (v[t] - mu) * rs * g[cb + t] + be[cb + t];
    of[base + t] = xv;
    ob[base + t] = f2bf(xv);
  }
}

// ---------------------------------------------------------------------------
// LN2: out = LN(f0 + f1 + b2 + x)
// ---------------------------------------------------------------------------
__global__ __launch_bounds__(256) void ln2_kernel(
    const float* __restrict__ f0, const u16* __restrict__ f1,
    const float* __restrict__ b2, const float* __restrict__ bsrc,
    const float* __restrict__ g, const float* __restrict__ be,
    float* __restrict__ of)
{
  const int row = blockIdx.x * 4 + (threadIdx.x >> 6);
  const int lane = threadIdx.x & 63;
  const size_t base = (size_t)row * 512 + lane * 8;
  const int cb = lane * 8;
  float v[8];
#pragma unroll
  for (int t = 0; t < 8; ++t)
    v[t] = f0[base + t] + bf2f(f1[base + t]) + b2[cb + t] + bsrc[base + t];
  float s = 0.f;
#pragma unroll
  for (int t = 0; t < 8; ++t) s += v[t];
#pragma unroll
  for (int off = 1; off < 64; off <<= 1) s += __shfl_xor(s, off, 64);
  const float mu = s * (1.0f / 512.0f);
  float qv = 0.f;
#pragma unroll
  for (int t = 0; t < 8; ++t) { float d = v[t] - mu; qv += d * d; }
#pragma unroll
  for (int off = 1; off < 64; off <<= 1) qv += __shfl_xor(qv, off, 64);
  const float rs = rsqrtf(qv * (1.0f / 512.0f) + 1e-5f);
#pragma unroll
  for (int t = 0; t < 8; ++t) {
    float xv = (v[t] - mu) * rs * g[cb + t] + be[cb + t];
    of[base + t] = xv;
  }
}

// ---------------------------------------------------------------------------
// prep kernels
// ---------------------------------------------------------------------------
__global__ __launch_bounds__(256) void cast_bf_kernel(
    const float* __restrict__ in, u16* __restrict__ out)
{
  const size_t i = ((size_t)blockIdx.x * 256 + threadIdx.x) * 8;
#pragma unroll
  for (int t = 0; t < 8; ++t) out[i + t] = f2bf(in[i + t]);
}

// Tiled transpose for the three 512x512 QKV weights in one launch (z = which).
__global__ __launch_bounds__(256) void transpose_qkv_kernel(
    const float* __restrict__ Wq, const float* __restrict__ Wk,
    const float* __restrict__ Wv, u16* __restrict__ dst)
{
  __shared__ u16 tile[32][33];
  const float* src = (blockIdx.z == 0) ? Wq : (blockIdx.z == 1) ? Wk : Wv;
  u16* d = dst + (size_t)blockIdx.z * 512 * 512;
  const int tx = threadIdx.x & 31, ty = threadIdx.x >> 5;
  const int n0 = blockIdx.x * 32, k0 = blockIdx.y * 32;
#pragma unroll
  for (int i = 0; i < 32; i += 8)
    tile[ty + i][tx] = f2bf(src[(size_t)(k0 + ty + i) * 512 + n0 + tx]);
  __syncthreads();
#pragma unroll
  for (int i = 0; i < 32; i += 8)
    d[(size_t)(n0 + ty + i) * 512 + k0 + tx] = tile[tx][ty + i];
}

__global__ __launch_bounds__(256) void transpose_bf_kernel(
    const float* __restrict__ src, u16* __restrict__ dst, int K, int N)
{
  __shared__ u16 tile[32][33];
  const int tx = threadIdx.x & 31, ty = threadIdx.x >> 5;
  const int n0 = blockIdx.x * 32, k0 = blockIdx.y * 32;
#pragma unroll
  for (int i = 0; i < 32; i += 8)
    tile[ty + i][tx] = f2bf(src[(size_t)(k0 + ty + i) * N + n0 + tx]);
  __syncthreads();
#pragma unroll
  for (int i = 0; i < 32; i += 8)
    dst[(size_t)(n0 + ty + i) * K + k0 + tx] = tile[tx][ty + i];
}

// ---------------------------------------------------------------------------
// launch
// ---------------------------------------------------------------------------
extern "C" void kernel_launch(void* const* d_in, const int* in_sizes, int n_in,
                              void* d_out, int out_size, void* d_ws, size_t ws_size,
                              hipStream_t stream) {
  const float* tokens = (const float*)d_in[0];
  const float* Wq = (const float*)d_in[1];
  const float* bq = (const float*)d_in[2];
  const float* Wk = (const float*)d_in[3];
  const float* bk = (const float*)d_in[4];
  const float* Wv = (const float*)d_in[5];
  const float* bv = (const float*)d_in[6];
  const float* dscale = (const float*)d_in[7];
  const float* W1 = (const float*)d_in[8];
  const float* b1 = (const float*)d_in[9];
  const float* W2 = (const float*)d_in[10];
  const float* b2 = (const float*)d_in[11];
  const float* g1 = (const float*)d_in[12];
  const float* be1 = (const float*)d_in[13];
  const float* g2 = (const float*)d_in[14];
  const float* be2 = (const float*)d_in[15];
  float* out = (float*)d_out;

  // Flat workspace layout (ws_size = 256 MiB). NO overlays.
  char* ws = (char*)d_ws;
  u16*   tok_bf = (u16*)(ws + 0);            //   8.4 MB
  u16*   wqkvT  = (u16*)(ws + 8388608);      //   1.6 MB
  u16*   w1T    = (u16*)(ws + 9961472);      //   2.1 MB
  u16*   w2T    = (u16*)(ws + 12058624);     //   2.1 MB
  u16*   qbuf   = (u16*)(ws + 14155776);     //   8.4 MB
  u16*   kbuf   = (u16*)(ws + 22544384);     //   8.4 MB
  u16*   vtbuf  = (u16*)(ws + 30932992);     //   8.4 MB
  u16*   Pbuf   = (u16*)(ws + 39321600);     //  64   MB (2 batches)
  float* y0buf  = (float*)(ws + 106430464);  //  16.8 MB
  u16*   y1buf  = (u16*)(ws + 123207680);    //   8.4 MB
  u16*   y2buf  = (u16*)(ws + 131596288);    //   8.4 MB
  u16*   y3buf  = (u16*)(ws + 139984896);    //   8.4 MB
  float* xf     = (float*)(ws + 148373504);  //  16.8 MB
  u16*   xbf    = (u16*)(ws + 165150720);    //   8.4 MB
  u16*   hbuf   = (u16*)(ws + 173539328);    //  33.6 MB
  float* f0buf  = (float*)(ws + 207093760);  //  16.8 MB
  u16*   f1buf  = (u16*)(ws + 223870976);    //   8.4 MB
  float* lbuf   = (float*)(ws + 232259584);  //  32 KB (ends 232292352 < 256 MiB)

  (void)hipMemsetAsync(lbuf, 0, 2 * 4096 * sizeof(float), stream);
  (void)hipMemsetAsync(y1buf, 0, (size_t)3 * 8388608, stream);  // y1,y2,y3 contiguous

  cast_bf_kernel<<<2048, 256, 0, stream>>>(tokens, tok_bf);
  transpose_qkv_kernel<<<dim3(16, 16, 3), 256, 0, stream>>>(Wq, Wk, Wv, wqkvT);
  transpose_bf_kernel<<<dim3(64, 16), 256, 0, stream>>>(W1, w1T, 512, 2048);
  transpose_bf_kernel<<<dim3(16, 64), 256, 0, stream>>>(W2, w2T, 2048, 512);

  gemm_qkv<<<dim3(12, 64), 256, 0, stream>>>(tok_bf, wqkvT, bq, bk, bv, qbuf, kbuf, vtbuf);

  // attention: both batches per launch
  gemm_qk_p<<<dim3(528, 2), 256, 0, stream>>>(qbuf, kbuf, dscale, Pbuf, lbuf);
  gemm_pv<<<dim3(4, 80, 2), 256, 0, stream>>>(Pbuf, vtbuf, y0buf, y1buf, y2buf, y3buf);

  ln1_kernel<<<2048, 256, 0, stream>>>(y0buf, y1buf, y2buf, y3buf, lbuf, tokens,
                                       g1, be1, xf, xbf);

  gemm_ffn1<<<dim3(16, 64), 256, 0, stream>>>(xbf, w1T, b1, hbuf);

  gemm_ffn2<<<dim3(4, 64, 2), 256, 0, stream>>>(hbuf, w2T, f0buf, f1buf);

  ln2_kernel<<<2048, 256, 0, stream>>>(f0buf, f1buf, b2, xf, g2, be2, out);
}